// Round 1
// baseline (110.058 us; speedup 1.0000x reference)
//
#include <hip/hip_runtime.h>
#include <hip/hip_bf16.h>

#define BC 4
#define NQ 1200
#define DIM 256
#define NH 8
#define HD 32
#define E3 768
#define MROWS (BC*NQ)
#define SCALE 0.17677669529663687f

typedef __attribute__((ext_vector_type(8))) short bf16x8;
typedef __attribute__((ext_vector_type(4))) float f32x4;

__device__ inline short f2bf(float f) {
    __hip_bfloat16 h = __float2bfloat16(f);
    return *reinterpret_cast<short*>(&h);
}

// ---------------- f32 -> bf16 convert (vectorized x4) ----------------
__global__ void cvt_kernel(const float* __restrict__ src, short* __restrict__ dst, int n4) {
    int i = blockIdx.x * blockDim.x + threadIdx.x;
    if (i >= n4) return;
    float4 v = reinterpret_cast<const float4*>(src)[i];
    short4 o;
    o.x = f2bf(v.x); o.y = f2bf(v.y); o.z = f2bf(v.z); o.w = f2bf(v.w);
    reinterpret_cast<short4*>(dst)[i] = o;
}

// ---------------- beta (f32 exact) + center packing ----------------
__global__ void beta_ctr_kernel(const float* __restrict__ feat, const float* __restrict__ bw,
                                const float* __restrict__ bb, const float* __restrict__ bbox,
                                float* __restrict__ beta, float* __restrict__ ctr) {
    int gw = (blockIdx.x * 256 + threadIdx.x) >> 6;   // one wave per (b,n)
    int lane = threadIdx.x & 63;
    if (gw >= MROWS) return;
    const float* frow = feat + (size_t)gw * DIM;
    float acc[NH];
#pragma unroll
    for (int h = 0; h < NH; ++h) acc[h] = 0.f;
#pragma unroll
    for (int it = 0; it < DIM / 64; ++it) {
        int d = it * 64 + lane;
        float f = frow[d];
#pragma unroll
        for (int h = 0; h < NH; ++h) acc[h] += f * bw[h * DIM + d];
    }
#pragma unroll
    for (int h = 0; h < NH; ++h) {
#pragma unroll
        for (int off = 32; off; off >>= 1) acc[h] += __shfl_xor(acc[h], off);
    }
    int b = gw / NQ, n = gw % NQ;
#pragma unroll
    for (int h = 0; h < NH; ++h) {
        float v = acc[h] + bb[h];
        if (lane == h) beta[(b * NH + h) * NQ + n] = v;
    }
    if (lane == 0) {
        ctr[gw * 2]     = bbox[(size_t)gw * 10];
        ctr[gw * 2 + 1] = bbox[(size_t)gw * 10 + 1];
    }
}

// ---------------- GEMM: C[M,E] = A[M,256](bf16) * W[E,256]^T + bias ----------------
// 64x64 tile, 4 waves, 16x16x32 bf16 MFMA. OUTF32: f32 out, else bf16.
template<bool OUTF32>
__global__ __launch_bounds__(256) void gemm_k256(const short* __restrict__ A,
                                                 const short* __restrict__ W,
                                                 const float* __restrict__ bias,
                                                 void* __restrict__ Cout, int Edim) {
    __shared__ short as[64][40];
    __shared__ short bs[64][40];
    int m0 = blockIdx.y * 64, e0 = blockIdx.x * 64;
    int t = threadIdx.x, lane = t & 63, wid = t >> 6;
    int wr = (wid >> 1) * 32, wc = (wid & 1) * 32;
    f32x4 acc[2][2] = {};
    int lrow = t >> 2, lch = t & 3;
    const short* Ag = A + (size_t)(m0 + lrow) * DIM + lch * 8;
    const short* Wg = W + (size_t)(e0 + lrow) * DIM + lch * 8;

    for (int ks = 0; ks < DIM / 32; ++ks) {
        bf16x8 av = *(const bf16x8*)(Ag + ks * 32);
        bf16x8 wv = *(const bf16x8*)(Wg + ks * 32);
        __syncthreads();
        *(bf16x8*)&as[lrow][lch * 8] = av;
        *(bf16x8*)&bs[lrow][lch * 8] = wv;
        __syncthreads();
#pragma unroll
        for (int sm = 0; sm < 2; ++sm) {
            bf16x8 af = *(const bf16x8*)&as[wr + sm * 16 + (lane & 15)][(lane >> 4) * 8];
#pragma unroll
            for (int sn = 0; sn < 2; ++sn) {
                bf16x8 bfv = *(const bf16x8*)&bs[wc + sn * 16 + (lane & 15)][(lane >> 4) * 8];
                acc[sm][sn] = __builtin_amdgcn_mfma_f32_16x16x32_bf16(af, bfv, acc[sm][sn], 0, 0, 0);
            }
        }
    }
#pragma unroll
    for (int sm = 0; sm < 2; ++sm)
#pragma unroll
        for (int sn = 0; sn < 2; ++sn) {
            int e = e0 + wc + sn * 16 + (lane & 15);
            float bv = bias[e];
#pragma unroll
            for (int r = 0; r < 4; ++r) {
                int m = m0 + wr + sm * 16 + (lane >> 4) * 4 + r;
                float v = acc[sm][sn][r] + bv;
                if (OUTF32) ((float*)Cout)[(size_t)m * Edim + e] = v;
                else        ((short*)Cout)[(size_t)m * Edim + e] = f2bf(v);
            }
        }
}

// ---------------- fused flash attention with distance-modulated mask ----------------
// grid: (ceil(N/64), B*H); block 256 = 4 waves x 16 q-rows each.
__global__ __launch_bounds__(256) void attn_kernel(const short* __restrict__ qkv,
                                                   const float* __restrict__ beta,
                                                   const float* __restrict__ ctr,
                                                   short* __restrict__ attnb) {
    __shared__ short kt[64][40];      // K tile [key][hd], padded
    __shared__ short vt[32][72];      // V tile transposed [hd][key], padded
    __shared__ float ckx[64], cky[64];
    __shared__ float cqx[64], cqy[64], bq[64];
    __shared__ short pl[4][16][72];   // per-wave P staging [q][key], padded

    int bh = blockIdx.y;
    int b = bh >> 3, h = bh & 7;
    int q0 = blockIdx.x * 64;
    int t = threadIdx.x, lane = t & 63, wid = t >> 6;
    int wq0 = wid * 16;

    if (t < 64) {
        int n = min(q0 + t, NQ - 1);
        cqx[t] = ctr[(b * NQ + n) * 2];
        cqy[t] = ctr[(b * NQ + n) * 2 + 1];
        bq[t]  = beta[(b * NH + h) * NQ + n];
    }

    int qrow = min(q0 + wq0 + (lane & 15), NQ - 1);
    bf16x8 qfrag = *(const bf16x8*)(qkv + (size_t)(b * NQ + qrow) * E3 + h * HD + (lane >> 4) * 8);

    float mrow[4], lsum[4];
    f32x4 o0 = {}, o1 = {};
#pragma unroll
    for (int r = 0; r < 4; ++r) { mrow[r] = -1e30f; lsum[r] = 0.f; }

    int lkrow = t >> 2, lch = t & 3;
    f32x4 zero = {};

    for (int kb = 0; kb < NQ; kb += 64) {
        __syncthreads();   // previous tile's reads done before overwrite
        int kn = min(kb + lkrow, NQ - 1);
        bf16x8 kv = *(const bf16x8*)(qkv + (size_t)(b * NQ + kn) * E3 + DIM + h * HD + lch * 8);
        bf16x8 vv = *(const bf16x8*)(qkv + (size_t)(b * NQ + kn) * E3 + 2 * DIM + h * HD + lch * 8);
        *(bf16x8*)&kt[lkrow][lch * 8] = kv;
#pragma unroll
        for (int j = 0; j < 8; ++j) vt[lch * 8 + j][lkrow] = vv[j];
        if (t < 64) {
            int kn2 = min(kb + t, NQ - 1);
            ckx[t] = ctr[(b * NQ + kn2) * 2];
            cky[t] = ctr[(b * NQ + kn2) * 2 + 1];
        }
        __syncthreads();

        float st[16];
#pragma unroll
        for (int kc = 0; kc < 4; ++kc) {
            bf16x8 kf = *(const bf16x8*)&kt[kc * 16 + (lane & 15)][(lane >> 4) * 8];
            f32x4 s = __builtin_amdgcn_mfma_f32_16x16x32_bf16(qfrag, kf, zero, 0, 0, 0);
            int keyl = kc * 16 + (lane & 15);
            bool kvalid = (kb + keyl) < NQ;
            float cx = ckx[keyl], cy = cky[keyl];
#pragma unroll
            for (int r = 0; r < 4; ++r) {
                int ql = wq0 + (lane >> 4) * 4 + r;
                float dx = cqx[ql] - cx, dy = cqy[ql] - cy;
                float dist = -sqrtf(dx * dx + dy * dy);
                float sc = s[r] * SCALE + dist * bq[ql];
                st[kc * 4 + r] = kvalid ? sc : -1e30f;
            }
        }
        // online softmax over this 64-key tile (rows live in 16-lane groups)
#pragma unroll
        for (int r = 0; r < 4; ++r) {
            float mt = fmaxf(fmaxf(st[r], st[4 + r]), fmaxf(st[8 + r], st[12 + r]));
#pragma unroll
            for (int off = 1; off < 16; off <<= 1) mt = fmaxf(mt, __shfl_xor(mt, off));
            float mnew = fmaxf(mrow[r], mt);
            float alpha = __expf(mrow[r] - mnew);
            mrow[r] = mnew;
            float rs = 0.f;
#pragma unroll
            for (int kc = 0; kc < 4; ++kc) {
                float p = __expf(st[kc * 4 + r] - mnew);
                st[kc * 4 + r] = p;
                rs += p;
            }
#pragma unroll
            for (int off = 1; off < 16; off <<= 1) rs += __shfl_xor(rs, off);
            lsum[r] = lsum[r] * alpha + rs;
            o0[r] *= alpha; o1[r] *= alpha;
        }
        // P -> LDS (bf16) to reach A-fragment layout
#pragma unroll
        for (int kc = 0; kc < 4; ++kc)
#pragma unroll
            for (int r = 0; r < 4; ++r)
                pl[wid][(lane >> 4) * 4 + r][kc * 16 + (lane & 15)] = f2bf(st[kc * 4 + r]);
        // PV
#pragma unroll
        for (int kc2 = 0; kc2 < 2; ++kc2) {
            bf16x8 pf  = *(const bf16x8*)&pl[wid][lane & 15][kc2 * 32 + (lane >> 4) * 8];
            bf16x8 vf0 = *(const bf16x8*)&vt[lane & 15][kc2 * 32 + (lane >> 4) * 8];
            bf16x8 vf1 = *(const bf16x8*)&vt[16 + (lane & 15)][kc2 * 32 + (lane >> 4) * 8];
            o0 = __builtin_amdgcn_mfma_f32_16x16x32_bf16(pf, vf0, o0, 0, 0, 0);
            o1 = __builtin_amdgcn_mfma_f32_16x16x32_bf16(pf, vf1, o1, 0, 0, 0);
        }
    }
#pragma unroll
    for (int r = 0; r < 4; ++r) {
        int qg = q0 + wq0 + (lane >> 4) * 4 + r;
        if (qg < NQ) {
            float inv = 1.f / lsum[r];
            attnb[(size_t)(b * NQ + qg) * DIM + h * HD + (lane & 15)]      = f2bf(o0[r] * inv);
            attnb[(size_t)(b * NQ + qg) * DIM + h * HD + 16 + (lane & 15)] = f2bf(o1[r] * inv);
        }
    }
}

extern "C" void kernel_launch(void* const* d_in, const int* in_sizes, int n_in,
                              void* d_out, int out_size, void* d_ws, size_t ws_size,
                              hipStream_t stream) {
    const float* bbox  = (const float*)d_in[0];
    const float* feat  = (const float*)d_in[1];
    const float* bw    = (const float*)d_in[2];
    const float* bb    = (const float*)d_in[3];
    const float* in_w  = (const float*)d_in[4];
    const float* in_b  = (const float*)d_in[5];
    const float* out_w = (const float*)d_in[6];
    const float* out_b = (const float*)d_in[7];
    float* out = (float*)d_out;

    char* ws = (char*)d_ws;
    size_t off = 0;
    auto alloc = [&](size_t bytes) { void* p = ws + off; off += (bytes + 255) & ~255ull; return p; };
    short* featb = (short*)alloc((size_t)MROWS * DIM * 2);
    short* wib   = (short*)alloc((size_t)E3 * DIM * 2);
    short* wob   = (short*)alloc((size_t)DIM * DIM * 2);
    short* qkvb  = (short*)alloc((size_t)MROWS * E3 * 2);
    short* attnb = (short*)alloc((size_t)MROWS * DIM * 2);
    float* beta  = (float*)alloc((size_t)BC * NH * NQ * 4);
    float* ctr   = (float*)alloc((size_t)BC * NQ * 2 * 4);
    (void)ws_size; (void)in_sizes; (void)n_in; (void)out_size;

    cvt_kernel<<<(MROWS * DIM / 4 + 255) / 256, 256, 0, stream>>>(feat, featb, MROWS * DIM / 4);
    cvt_kernel<<<(E3 * DIM / 4 + 255) / 256, 256, 0, stream>>>(in_w, wib, E3 * DIM / 4);
    cvt_kernel<<<(DIM * DIM / 4 + 255) / 256, 256, 0, stream>>>(out_w, wob, DIM * DIM / 4);
    beta_ctr_kernel<<<MROWS / 4, 256, 0, stream>>>(feat, bw, bb, bbox, beta, ctr);
    gemm_k256<false><<<dim3(E3 / 64, MROWS / 64), 256, 0, stream>>>(featb, wib, in_b, qkvb, E3);
    attn_kernel<<<dim3((NQ + 63) / 64, BC * NH), 256, 0, stream>>>(qkvb, beta, ctr, attnb);
    gemm_k256<true><<<dim3(DIM / 64, MROWS / 64), 256, 0, stream>>>(attnb, wob, out_b, out, DIM);
}

// Round 2
// 68.202 us; speedup vs baseline: 1.6137x; 1.6137x over previous
//
#include <hip/hip_runtime.h>
#include <hip/hip_bf16.h>

#define BC 4
#define NQ 1200
#define DIM 256
#define NH 8
#define HD 32
#define E3 768
#define MROWS (BC*NQ)
#define SCALE 0.17677669529663687f
#define L2E 1.4426950408889634f

typedef __attribute__((ext_vector_type(8))) short bf16x8;
typedef __attribute__((ext_vector_type(4))) float f32x4;

__device__ inline short f2bf(float f) {
    __hip_bfloat16 h = __float2bfloat16(f);
    return *reinterpret_cast<short*>(&h);
}
__device__ inline unsigned pack2bf(float a, float b) {
    unsigned ua = (unsigned short)f2bf(a);
    unsigned ub = (unsigned short)f2bf(b);
    return ua | (ub << 16);
}

// ---------------- beta (f32 exact) + center packing ----------------
__global__ void beta_ctr_kernel(const float* __restrict__ feat, const float* __restrict__ bw,
                                const float* __restrict__ bb, const float* __restrict__ bbox,
                                float* __restrict__ beta, float* __restrict__ ctr) {
    int gw = (blockIdx.x * 256 + threadIdx.x) >> 6;   // one wave per (b,n)
    int lane = threadIdx.x & 63;
    if (gw >= MROWS) return;
    const float* frow = feat + (size_t)gw * DIM;
    float acc[NH];
#pragma unroll
    for (int h = 0; h < NH; ++h) acc[h] = 0.f;
#pragma unroll
    for (int it = 0; it < DIM / 64; ++it) {
        int d = it * 64 + lane;
        float f = frow[d];
#pragma unroll
        for (int h = 0; h < NH; ++h) acc[h] += f * bw[h * DIM + d];
    }
#pragma unroll
    for (int h = 0; h < NH; ++h) {
#pragma unroll
        for (int off = 32; off; off >>= 1) acc[h] += __shfl_xor(acc[h], off);
    }
    int b = gw / NQ, n = gw % NQ;
#pragma unroll
    for (int h = 0; h < NH; ++h) {
        float v = acc[h] + bb[h];
        if (lane == h) beta[(b * NH + h) * NQ + n] = v;
    }
    if (lane == 0) {
        ctr[gw * 2]     = bbox[(size_t)gw * 10];
        ctr[gw * 2 + 1] = bbox[(size_t)gw * 10 + 1];
    }
}

// ---------------- GEMM: C[M,E] = A[M,256] * W[E,256]^T + bias ----------------
// 64x64 tile, 4 waves, 16x16x32 bf16 MFMA. AF32/BF32: stage-convert f32->bf16.
template<bool AF32, bool BF32, bool OUTF32>
__global__ __launch_bounds__(256) void gemm_k256(const void* __restrict__ Av,
                                                 const void* __restrict__ Bv,
                                                 const float* __restrict__ bias,
                                                 void* __restrict__ Cout, int Edim) {
    __shared__ short as[64][40];
    __shared__ short bs[64][40];
    int m0 = blockIdx.y * 64, e0 = blockIdx.x * 64;
    int t = threadIdx.x, lane = t & 63, wid = t >> 6;
    int wr = (wid >> 1) * 32, wc = (wid & 1) * 32;
    f32x4 acc[2][2] = {};
    int lrow = t >> 2, lch = t & 3;

    for (int ks = 0; ks < DIM / 32; ++ks) {
        bf16x8 av, wv;
        if (AF32) {
            const float* A = (const float*)Av;
            float4 f0 = *(const float4*)(A + (size_t)(m0 + lrow) * DIM + ks * 32 + lch * 8);
            float4 f1 = *(const float4*)(A + (size_t)(m0 + lrow) * DIM + ks * 32 + lch * 8 + 4);
            av[0]=f2bf(f0.x); av[1]=f2bf(f0.y); av[2]=f2bf(f0.z); av[3]=f2bf(f0.w);
            av[4]=f2bf(f1.x); av[5]=f2bf(f1.y); av[6]=f2bf(f1.z); av[7]=f2bf(f1.w);
        } else {
            av = *(const bf16x8*)((const short*)Av + (size_t)(m0 + lrow) * DIM + ks * 32 + lch * 8);
        }
        if (BF32) {
            const float* B = (const float*)Bv;
            float4 f0 = *(const float4*)(B + (size_t)(e0 + lrow) * DIM + ks * 32 + lch * 8);
            float4 f1 = *(const float4*)(B + (size_t)(e0 + lrow) * DIM + ks * 32 + lch * 8 + 4);
            wv[0]=f2bf(f0.x); wv[1]=f2bf(f0.y); wv[2]=f2bf(f0.z); wv[3]=f2bf(f0.w);
            wv[4]=f2bf(f1.x); wv[5]=f2bf(f1.y); wv[6]=f2bf(f1.z); wv[7]=f2bf(f1.w);
        } else {
            wv = *(const bf16x8*)((const short*)Bv + (size_t)(e0 + lrow) * DIM + ks * 32 + lch * 8);
        }
        __syncthreads();
        *(bf16x8*)&as[lrow][lch * 8] = av;
        *(bf16x8*)&bs[lrow][lch * 8] = wv;
        __syncthreads();
#pragma unroll
        for (int sm = 0; sm < 2; ++sm) {
            bf16x8 af = *(const bf16x8*)&as[wr + sm * 16 + (lane & 15)][(lane >> 4) * 8];
#pragma unroll
            for (int sn = 0; sn < 2; ++sn) {
                bf16x8 bfv = *(const bf16x8*)&bs[wc + sn * 16 + (lane & 15)][(lane >> 4) * 8];
                acc[sm][sn] = __builtin_amdgcn_mfma_f32_16x16x32_bf16(af, bfv, acc[sm][sn], 0, 0, 0);
            }
        }
    }
#pragma unroll
    for (int sm = 0; sm < 2; ++sm)
#pragma unroll
        for (int sn = 0; sn < 2; ++sn) {
            int e = e0 + wc + sn * 16 + (lane & 15);
            float bv = bias[e];
#pragma unroll
            for (int r = 0; r < 4; ++r) {
                int m = m0 + wr + sm * 16 + (lane >> 4) * 4 + r;
                float v = acc[sm][sn][r] + bv;
                if (OUTF32) ((float*)Cout)[(size_t)m * Edim + e] = v;
                else        ((short*)Cout)[(size_t)m * Edim + e] = f2bf(v);
            }
        }
}

// ---------------- fused flash attention, swapped-QK^T, 2-way key split ----------------
// grid: (ceil(N/32), B*H); block 256 = 4 waves: wave = (qgroup<<1)|ksplit.
// Each wave: 16 q-rows (one per lane&15), 64-key subtiles; merge splits in LDS at end.
__global__ __launch_bounds__(256) void attn_kernel(const short* __restrict__ qkv,
                                                   const float* __restrict__ beta,
                                                   const float* __restrict__ ctr,
                                                   short* __restrict__ attnb) {
    __shared__ short kt[128][40];      // K tile [key][hd]; reused as merge buffer at end
    __shared__ short vt[32][136];      // V^T tile [hd][key]
    __shared__ float2 ckv[128];        // key centers
    __shared__ short pl[4][16][72];    // per-wave P staging [q][key]

    const int t = threadIdx.x, lane = t & 63, w = t >> 6;
    const int g = lane >> 4, i = lane & 15;
    const int qg = w >> 1, ksp = w & 1;
    const int bh = blockIdx.y, b = bh >> 3, h = bh & 7;
    const int q0 = blockIdx.x * 32 + qg * 16;
    const int q = q0 + i, qc = min(q, NQ - 1);
    const int kwb = ksp * 64;

    bf16x8 qf = *(const bf16x8*)(qkv + (size_t)(b * NQ + qc) * E3 + h * HD + g * 8);
    const float cqx = ctr[(b * NQ + qc) * 2];
    const float cqy = ctr[(b * NQ + qc) * 2 + 1];
    const float bql = beta[(b * NH + h) * NQ + qc] * L2E;
    const float SL2E = SCALE * L2E;

    float mcur = -1e30f, lsum = 0.f;
    f32x4 o0 = {}, o1 = {};
    f32x4 zero = {};

    const int skey = t >> 1, shalf = t & 1;
    const short* kbase = qkv + (size_t)b * NQ * E3 + DIM + h * HD + shalf * 16;
    const short* vbase = qkv + (size_t)b * NQ * E3 + 2 * DIM + h * HD + shalf * 16;

    for (int kb = 0; kb < NQ; kb += 128) {
        __syncthreads();
        {
            int kn = min(kb + skey, NQ - 1);
            bf16x8 kv0 = *(const bf16x8*)(kbase + (size_t)kn * E3);
            bf16x8 kv1 = *(const bf16x8*)(kbase + (size_t)kn * E3 + 8);
            bf16x8 vv0 = *(const bf16x8*)(vbase + (size_t)kn * E3);
            bf16x8 vv1 = *(const bf16x8*)(vbase + (size_t)kn * E3 + 8);
            *(bf16x8*)&kt[skey][shalf * 16]     = kv0;
            *(bf16x8*)&kt[skey][shalf * 16 + 8] = kv1;
#pragma unroll
            for (int j = 0; j < 8; ++j) vt[shalf * 16 + j][skey]     = vv0[j];
#pragma unroll
            for (int j = 0; j < 8; ++j) vt[shalf * 16 + 8 + j][skey] = vv1[j];
            if (t < 128) {
                int c = min(kb + t, NQ - 1);
                ckv[t] = make_float2(ctr[(b * NQ + c) * 2], ctr[(b * NQ + c) * 2 + 1]);
            }
        }
        __syncthreads();

        float st[16];
#pragma unroll
        for (int kc = 0; kc < 4; ++kc) {
            bf16x8 af = *(const bf16x8*)&kt[kwb + kc * 16 + i][g * 8];
            f32x4 s = __builtin_amdgcn_mfma_f32_16x16x32_bf16(af, qf, zero, 0, 0, 0);
            float4 c01 = *(const float4*)&ckv[kwb + kc * 16 + 4 * g];
            float4 c23 = *(const float4*)&ckv[kwb + kc * 16 + 4 * g + 2];
            int kg0 = kb + kwb + kc * 16 + 4 * g;
            float cx[4] = {c01.x, c01.z, c23.x, c23.z};
            float cy[4] = {c01.y, c01.w, c23.y, c23.w};
#pragma unroll
            for (int r = 0; r < 4; ++r) {
                float dx = cqx - cx[r], dy = cqy - cy[r];
                float dist = __builtin_amdgcn_sqrtf(dx * dx + dy * dy);
                float sc = s[r] * SL2E - dist * bql;
                st[kc * 4 + r] = (kg0 + r < NQ) ? sc : -1e30f;
            }
        }
        // tile max over 64 keys: 15 in-lane + 2 shfl (lanes i, i+16, i+32, i+48 share q)
        float vm = st[0];
#pragma unroll
        for (int x = 1; x < 16; ++x) vm = fmaxf(vm, st[x]);
        vm = fmaxf(vm, __shfl_xor(vm, 16));
        vm = fmaxf(vm, __shfl_xor(vm, 32));
        float mnew = fmaxf(mcur, vm);
        float alpha = __builtin_amdgcn_exp2f(mcur - mnew);
        mcur = mnew;
        float rs = 0.f;
#pragma unroll
        for (int x = 0; x < 16; ++x) {
            st[x] = __builtin_amdgcn_exp2f(st[x] - mnew);
            rs += st[x];
        }
        rs += __shfl_xor(rs, 16);
        rs += __shfl_xor(rs, 32);
        lsum = lsum * alpha + rs;
#pragma unroll
        for (int r = 0; r < 4; ++r) { o0[r] *= alpha; o1[r] *= alpha; }
        // pack P -> per-wave LDS (dword writes)
#pragma unroll
        for (int kc = 0; kc < 4; ++kc) {
            *(unsigned*)&pl[w][i][kc * 16 + 4 * g]     = pack2bf(st[kc * 4 + 0], st[kc * 4 + 1]);
            *(unsigned*)&pl[w][i][kc * 16 + 4 * g + 2] = pack2bf(st[kc * 4 + 2], st[kc * 4 + 3]);
        }
        // PV: O^T += V^T * P^T
#pragma unroll
        for (int kc2 = 0; kc2 < 2; ++kc2) {
            bf16x8 pf  = *(const bf16x8*)&pl[w][i][kc2 * 32 + g * 8];
            bf16x8 vf0 = *(const bf16x8*)&vt[i][kwb + kc2 * 32 + g * 8];
            bf16x8 vf1 = *(const bf16x8*)&vt[16 + i][kwb + kc2 * 32 + g * 8];
            o0 = __builtin_amdgcn_mfma_f32_16x16x32_bf16(vf0, pf, o0, 0, 0, 0);
            o1 = __builtin_amdgcn_mfma_f32_16x16x32_bf16(vf1, pf, o1, 0, 0, 0);
        }
    }

    // merge the two key-splits per q-group (reuse kt memory)
    __syncthreads();
    float* mrg = (float*)&kt[0][0];            // [4 waves][64 lanes][10]
    float* my = mrg + (w * 64 + lane) * 10;
    my[0] = mcur; my[1] = lsum;
#pragma unroll
    for (int r = 0; r < 4; ++r) { my[2 + r] = o0[r]; my[6 + r] = o1[r]; }
    __syncthreads();
    const float* pr = mrg + ((w ^ 1) * 64 + lane) * 10;
    float m2 = pr[0], l2 = pr[1];
    float mN = fmaxf(mcur, m2);
    float a1 = __builtin_amdgcn_exp2f(mcur - mN);
    float a2 = __builtin_amdgcn_exp2f(m2 - mN);
    float inv = 1.f / (lsum * a1 + l2 * a2);
    int hh = w & 1;                            // this wave writes d-half hh
    f32x4 mine = hh ? o1 : o0;
    if (q < NQ) {
        short4 outv;
        float vals[4];
#pragma unroll
        for (int r = 0; r < 4; ++r) vals[r] = (mine[r] * a1 + pr[2 + hh * 4 + r] * a2) * inv;
        outv.x = f2bf(vals[0]); outv.y = f2bf(vals[1]);
        outv.z = f2bf(vals[2]); outv.w = f2bf(vals[3]);
        *(short4*)&attnb[(size_t)(b * NQ + q) * DIM + h * HD + hh * 16 + 4 * g] = outv;
    }
}

extern "C" void kernel_launch(void* const* d_in, const int* in_sizes, int n_in,
                              void* d_out, int out_size, void* d_ws, size_t ws_size,
                              hipStream_t stream) {
    const float* bbox  = (const float*)d_in[0];
    const float* feat  = (const float*)d_in[1];
    const float* bw    = (const float*)d_in[2];
    const float* bb    = (const float*)d_in[3];
    const float* in_w  = (const float*)d_in[4];
    const float* in_b  = (const float*)d_in[5];
    const float* out_w = (const float*)d_in[6];
    const float* out_b = (const float*)d_in[7];
    float* out = (float*)d_out;

    char* ws = (char*)d_ws;
    size_t off = 0;
    auto alloc = [&](size_t bytes) { void* p = ws + off; off += (bytes + 255) & ~255ull; return p; };
    short* qkvb  = (short*)alloc((size_t)MROWS * E3 * 2);
    short* attnb = (short*)alloc((size_t)MROWS * DIM * 2);
    float* betab = (float*)alloc((size_t)BC * NH * NQ * 4);
    float* ctr   = (float*)alloc((size_t)BC * NQ * 2 * 4);
    (void)ws_size; (void)in_sizes; (void)n_in; (void)out_size;

    beta_ctr_kernel<<<MROWS / 4, 256, 0, stream>>>(feat, bw, bb, bbox, betab, ctr);
    gemm_k256<true, true, false><<<dim3(E3 / 64, MROWS / 64), 256, 0, stream>>>(feat, in_w, in_b, qkvb, E3);
    attn_kernel<<<dim3((NQ + 31) / 32, BC * NH), 256, 0, stream>>>(qkvb, betab, ctr, attnb);
    gemm_k256<false, true, true><<<dim3(DIM / 64, MROWS / 64), 256, 0, stream>>>(attnb, out_w, out_b, out, DIM);
}